// Round 2
// baseline (603.228 us; speedup 1.0000x reference)
//
#include <hip/hip_runtime.h>
#include <math.h>

#define NPROJ 16
#define NBINS 65536
#define WD (NBINS - 6)
#define B_ 2
#define C_ 3
#define H_ 384
#define W_ 384
#define HO 378
#define NPAT (HO * HO)            // 142884
#define DF (C_ * 7 * 7)           // 147
#define BP (B_ * NPROJ)           // 32

// ---------- float <-> monotone-unsigned key (for atomic min/max on floats) ----
__device__ inline unsigned f2key(float f) {
    unsigned u = __float_as_uint(f);
    return (u & 0x80000000u) ? ~u : (u | 0x80000000u);
}
__device__ inline float key2f(unsigned k) {
    unsigned u = (k & 0x80000000u) ? (k ^ 0x80000000u) : ~k;
    return __uint_as_float(u);
}

// ---------- K0: r = rand / std(rand, axis=d, ddof=1); also init keys/loss ----
__global__ __launch_bounds__(64) void k_rnorm(const float* __restrict__ rnd,
                                              float* __restrict__ rnorm,
                                              unsigned* __restrict__ keys,
                                              float* __restrict__ loss) {
    int bp = blockIdx.x;               // b*NPROJ + p
    int b = bp / NPROJ, p = bp % NPROJ;
    int lane = threadIdx.x;
    if (lane == 0) {
        keys[2 * bp] = 0xFFFFFFFFu;    // min key
        keys[2 * bp + 1] = 0u;         // max key
        loss[bp] = 0.f;
    }
    float s = 0.f, s2 = 0.f;
    for (int d = lane; d < DF; d += 64) {
        float v = rnd[((size_t)b * DF + d) * NPROJ + p];
        s += v; s2 += v * v;
    }
    for (int o = 32; o > 0; o >>= 1) { s += __shfl_down(s, o); s2 += __shfl_down(s2, o); }
    s = __shfl(s, 0); s2 = __shfl(s2, 0);
    float mean = s / (float)DF;
    float var = (s2 - (float)DF * mean * mean) / (float)(DF - 1);
    float inv = 1.0f / sqrtf(var);
    for (int d = lane; d < DF; d += 64) {
        size_t idx = ((size_t)b * DF + d) * NPROJ + p;
        rnorm[idx] = rnd[idx] * inv;
    }
}

// ---------- K1: patch projection (7x7x3 conv, 16 outputs) + fused min/max ----
// grid: (12, 12, 2*B_)  block: 256.  blockIdx.z: bit0 = which image, rest = b.
__global__ __launch_bounds__(256) void k_proj(const float* __restrict__ ximg,
                                              const float* __restrict__ yimg,
                                              const float* __restrict__ rnorm,
                                              float* __restrict__ proj_x,
                                              float* __restrict__ proj_y,
                                              unsigned* __restrict__ keys) {
    const int TILE = 32;
    __shared__ float tile[C_][TILE + 6][TILE + 6];
    __shared__ float wlds[DF][NPROJ];
    __shared__ float smn[4][NPROJ], smx[4][NPROJ];
    int bz = blockIdx.z;
    int b = bz >> 1;
    const float* img = (bz & 1) ? yimg : ximg;
    float* proj = (bz & 1) ? proj_y : proj_x;
    int tid = threadIdx.x;

    for (int i = tid; i < DF * NPROJ; i += 256)
        ((float*)wlds)[i] = rnorm[(size_t)b * DF * NPROJ + i];

    int h0 = blockIdx.y * TILE, w0 = blockIdx.x * TILE;
    for (int c = 0; c < C_; c++)
        for (int i = tid; i < (TILE + 6) * (TILE + 6); i += 256) {
            int r = i / (TILE + 6), col = i % (TILE + 6);
            int h = h0 + r, w = w0 + col;
            tile[c][r][col] = (h < H_ && w < W_)
                ? img[((size_t)(b * C_ + c) * H_ + h) * W_ + w] : 0.f;
        }
    __syncthreads();

    int tx = tid & 31, ty = tid >> 5;   // ty in 0..7, 4 pixel rows per thread
    float acc[4][NPROJ];
#pragma unroll
    for (int q = 0; q < 4; q++)
#pragma unroll
        for (int p = 0; p < NPROJ; p++) acc[q][p] = 0.f;

    for (int c = 0; c < C_; c++)
        for (int i = 0; i < 7; i++)
            for (int j = 0; j < 7; j++) {
                const float* wp = &wlds[c * 49 + i * 7 + j][0];
                float wv[NPROJ];
#pragma unroll
                for (int p = 0; p < NPROJ; p++) wv[p] = wp[p];
#pragma unroll
                for (int q = 0; q < 4; q++) {
                    float pix = tile[c][ty + 8 * q + i][tx + j];
#pragma unroll
                    for (int p = 0; p < NPROJ; p++)
                        acc[q][p] = fmaf(pix, wv[p], acc[q][p]);
                }
            }

    float pmn[NPROJ], pmx[NPROJ];
#pragma unroll
    for (int p = 0; p < NPROJ; p++) { pmn[p] = INFINITY; pmx[p] = -INFINITY; }

#pragma unroll
    for (int q = 0; q < 4; q++) {
        int ho = h0 + ty + 8 * q, wo = w0 + tx;
        if (ho < HO && wo < HO) {
            size_t n = (size_t)ho * HO + wo;
#pragma unroll
            for (int p = 0; p < NPROJ; p++) {
                float v = acc[q][p];
                pmn[p] = fminf(pmn[p], v);
                pmx[p] = fmaxf(pmx[p], v);
                proj[((size_t)(b * NPROJ + p)) * NPAT + n] = v;
            }
        }
    }

    // wave butterfly reduce per projection
    for (int o = 1; o < 64; o <<= 1) {
#pragma unroll
        for (int p = 0; p < NPROJ; p++) {
            pmn[p] = fminf(pmn[p], __shfl_xor(pmn[p], o));
            pmx[p] = fmaxf(pmx[p], __shfl_xor(pmx[p], o));
        }
    }
    int lane = tid & 63, wv = tid >> 6;
    if (lane == 0) {
#pragma unroll
        for (int p = 0; p < NPROJ; p++) { smn[wv][p] = pmn[p]; smx[wv][p] = pmx[p]; }
    }
    __syncthreads();
    if (tid < NPROJ) {
        float mn = fminf(fminf(smn[0][tid], smn[1][tid]), fminf(smn[2][tid], smn[3][tid]));
        float mx = fmaxf(fmaxf(smx[0][tid], smx[1][tid]), fmaxf(smx[2][tid], smx[3][tid]));
        atomicMin(&keys[2 * (b * NPROJ + tid)], f2key(mn));
        atomicMax(&keys[2 * (b * NPROJ + tid) + 1], f2key(mx));
    }
}

// ---------- K2: fused scatter pass ------------------------------------------
// y-hist: idempotent set 1.0 (plain stores). px: bilinear-weight scatter via
// fire-and-forget atomicAdd (no return latency, unlike the old gather).
__global__ __launch_bounds__(256) void k_scatter2(const float* __restrict__ px,
                                                  const float* __restrict__ py,
                                                  const unsigned* __restrict__ keys,
                                                  float* __restrict__ hist,
                                                  float* __restrict__ wa) {
    int bp = blockIdx.y;
    float mn = key2f(keys[2 * bp]);
    float mx = key2f(keys[2 * bp + 1]);
    float scale = mx - mn;
    const float* srcy = py + (size_t)bp * NPAT;
    const float* srcx = px + (size_t)bp * NPAT;
    float* h = hist + (size_t)bp * NBINS;
    float* w = wa + (size_t)bp * WD;
    for (int i = blockIdx.x * blockDim.x + threadIdx.x; i < NPAT;
         i += gridDim.x * blockDim.x) {
        float yv = srcy[i];
        int idx = (int)floorf((float)(NBINS - 1) * (yv - mn) / scale);
        idx = min(max(idx, 0), NBINS - 1);
        h[idx] = 1.0f;

        float xv = srcx[i];
        float t = (xv - mn) / scale;
        float ix = t * (float)WD - 0.5f;
        float x0 = floorf(ix);
        float w1 = ix - x0;
        int x0i = (int)x0;
        if (x0i >= 0 && x0i < WD) atomicAdd(&w[x0i], 1.0f - w1);
        int x1i = x0i + 1;
        if (x1i >= 0 && x1i < WD) atomicAdd(&w[x1i], w1);
    }
}

// ---------- K3: conv(7-tap) + clamp + dot with weights, reduce to loss -------
__global__ __launch_bounds__(256) void k_convdot(const float* __restrict__ hist,
                                                 const float* __restrict__ wa,
                                                 float* __restrict__ loss) {
    int bp = blockIdx.y;
    int w = blockIdx.x * blockDim.x + threadIdx.x;
    float acc = 0.f;
    if (w < WD) {
        const float* h = hist + (size_t)bp * NBINS;
        float s = 0.f;
#pragma unroll
        for (int k = 0; k < 7; k++) {
            float d = (float)(k - 3);
            // reference: exp((x)^2 / (-2*1.2^2)) ** 2  == exp(-x^2/1.44)
            float g = expf(-d * d / 1.44f);
            s += h[w + k] * g;
        }
        s = fminf(s, 1.0f);
        acc = s * wa[(size_t)bp * WD + w];
    }
    for (int o = 32; o > 0; o >>= 1) acc += __shfl_down(acc, o);
    __shared__ float sacc[4];
    int wv = threadIdx.x >> 6;
    if ((threadIdx.x & 63) == 0) sacc[wv] = acc;
    __syncthreads();
    if (threadIdx.x == 0) {
        float t = sacc[0] + sacc[1] + sacc[2] + sacc[3];
        atomicAdd(&loss[bp], t);
    }
}

// ---------- K4: finalize -----------------------------------------------------
__global__ void k_final(const float* __restrict__ loss, float* __restrict__ out) {
    float s = 0.f;
    for (int i = 0; i < BP; i++) s += loss[i];
    out[0] = -s / (float)(B_ * NPROJ);
}

extern "C" void kernel_launch(void* const* d_in, const int* in_sizes, int n_in,
                              void* d_out, int out_size, void* d_ws, size_t ws_size,
                              hipStream_t stream) {
    (void)in_sizes; (void)n_in; (void)out_size; (void)ws_size;
    const float* x = (const float*)d_in[0];
    const float* y = (const float*)d_in[1];
    const float* rnd = (const float*)d_in[2];
    float* out = (float*)d_out;

    float* ws = (float*)d_ws;
    float* rnorm = ws;                                     // 4704
    float* px = rnorm + (size_t)B_ * DF * NPROJ;           // BP*NPAT
    float* py = px + (size_t)BP * NPAT;                    // BP*NPAT
    float* hist = py + (size_t)BP * NPAT;                  // BP*NBINS
    float* wa = hist + (size_t)BP * NBINS;                 // BP*WD
    unsigned* keys = (unsigned*)(wa + (size_t)BP * WD);    // 2*BP uints
    float* loss = (float*)(keys + 2 * BP);                 // BP

    k_rnorm<<<BP, 64, 0, stream>>>(rnd, rnorm, keys, loss);

    dim3 pgrid((HO + 31) / 32, (HO + 31) / 32, 2 * B_);
    k_proj<<<pgrid, 256, 0, stream>>>(x, y, rnorm, px, py, keys);

    // zero hist + wa in one shot (they are adjacent)
    hipMemsetAsync(hist, 0, ((size_t)BP * NBINS + (size_t)BP * WD) * sizeof(float), stream);

    k_scatter2<<<dim3(128, BP), 256, 0, stream>>>(px, py, keys, hist, wa);
    k_convdot<<<dim3((WD + 255) / 256, BP), 256, 0, stream>>>(hist, wa, loss);
    k_final<<<1, 1, 0, stream>>>(loss, out);
}

// Round 4
// 162.157 us; speedup vs baseline: 3.7200x; 3.7200x over previous
//
#include <hip/hip_runtime.h>
#include <math.h>

#define NPROJ 16
#define NBINS 65536
#define WD (NBINS - 6)
#define NB2 (NBINS + 16)      // hist stride: 8 front pad + NBINS + 8 back pad
#define B_ 2
#define C_ 3
#define H_ 384
#define W_ 384
#define HO 378
#define NPAT (HO * HO)        // 142884 (divisible by 4)
#define DF 147                // 3*7*7
#define BP 32                 // B_*NPROJ

__device__ inline unsigned f2key(float f) {
    unsigned u = __float_as_uint(f);
    return (u & 0x80000000u) ? ~u : (u | 0x80000000u);
}
__device__ inline float key2f(unsigned k) {
    unsigned u = (k & 0x80000000u) ? (k ^ 0x80000000u) : ~k;
    return __uint_as_float(u);
}

// ---------- K0: rand/std (ddof=1); init keys; zero out -----------------------
__global__ __launch_bounds__(64) void k_rnorm(const float* __restrict__ rnd,
                                              float* __restrict__ rnorm,
                                              unsigned* __restrict__ keys,
                                              float* __restrict__ out) {
    int bp = blockIdx.x;               // b*NPROJ + p
    int b = bp / NPROJ, p = bp % NPROJ;
    int lane = threadIdx.x;
    if (lane == 0) {
        keys[2 * bp] = 0xFFFFFFFFu;    // min key
        keys[2 * bp + 1] = 0u;         // max key
        if (bp == 0) out[0] = 0.f;     // accumulated atomically in k_gatherconv
    }
    float s = 0.f, s2 = 0.f;
    for (int d = lane; d < DF; d += 64) {
        float v = rnd[((size_t)b * DF + d) * NPROJ + p];
        s += v; s2 += v * v;
    }
    for (int o = 32; o > 0; o >>= 1) { s += __shfl_down(s, o); s2 += __shfl_down(s2, o); }
    s = __shfl(s, 0); s2 = __shfl(s2, 0);
    float mean = s / (float)DF;
    float var = (s2 - (float)DF * mean * mean) / (float)(DF - 1);
    float inv = 1.0f / sqrtf(var);
    for (int d = lane; d < DF; d += 64) {
        size_t idx = ((size_t)b * DF + d) * NPROJ + p;
        rnorm[idx] = rnd[idx] * inv;
    }
}

// ---------- K1: patch projection (7x7x3 conv, 16 outputs) + fused min/max ----
__global__ __launch_bounds__(256) void k_proj(const float* __restrict__ ximg,
                                              const float* __restrict__ yimg,
                                              const float* __restrict__ rnorm,
                                              float* __restrict__ proj_x,
                                              float* __restrict__ proj_y,
                                              unsigned* __restrict__ keys) {
    const int TILE = 32;
    __shared__ float tile[C_][TILE + 6][TILE + 6];
    __shared__ float wlds[DF][NPROJ];
    __shared__ float smn[4][NPROJ], smx[4][NPROJ];
    int bz = blockIdx.z;
    int b = bz >> 1;
    const float* img = (bz & 1) ? yimg : ximg;
    float* proj = (bz & 1) ? proj_y : proj_x;
    int tid = threadIdx.x;

    for (int i = tid; i < DF * NPROJ; i += 256)
        ((float*)wlds)[i] = rnorm[(size_t)b * DF * NPROJ + i];

    int h0 = blockIdx.y * TILE, w0 = blockIdx.x * TILE;
    for (int c = 0; c < C_; c++)
        for (int i = tid; i < (TILE + 6) * (TILE + 6); i += 256) {
            int r = i / (TILE + 6), col = i % (TILE + 6);
            int h = h0 + r, w = w0 + col;
            tile[c][r][col] = (h < H_ && w < W_)
                ? img[((size_t)(b * C_ + c) * H_ + h) * W_ + w] : 0.f;
        }
    __syncthreads();

    int tx = tid & 31, ty = tid >> 5;   // 4 pixel rows per thread
    float acc[4][NPROJ];
#pragma unroll
    for (int q = 0; q < 4; q++)
#pragma unroll
        for (int p = 0; p < NPROJ; p++) acc[q][p] = 0.f;

    for (int c = 0; c < C_; c++)
        for (int i = 0; i < 7; i++)
            for (int j = 0; j < 7; j++) {
                const float* wp = &wlds[c * 49 + i * 7 + j][0];
                float wv[NPROJ];
#pragma unroll
                for (int p = 0; p < NPROJ; p++) wv[p] = wp[p];
#pragma unroll
                for (int q = 0; q < 4; q++) {
                    float pix = tile[c][ty + 8 * q + i][tx + j];
#pragma unroll
                    for (int p = 0; p < NPROJ; p++)
                        acc[q][p] = fmaf(pix, wv[p], acc[q][p]);
                }
            }

    float pmn[NPROJ], pmx[NPROJ];
#pragma unroll
    for (int p = 0; p < NPROJ; p++) { pmn[p] = INFINITY; pmx[p] = -INFINITY; }

#pragma unroll
    for (int q = 0; q < 4; q++) {
        int ho = h0 + ty + 8 * q, wo = w0 + tx;
        if (ho < HO && wo < HO) {
            size_t n = (size_t)ho * HO + wo;
#pragma unroll
            for (int p = 0; p < NPROJ; p++) {
                float v = acc[q][p];
                pmn[p] = fminf(pmn[p], v);
                pmx[p] = fmaxf(pmx[p], v);
                proj[((size_t)(b * NPROJ + p)) * NPAT + n] = v;
            }
        }
    }

    for (int o = 1; o < 64; o <<= 1) {
#pragma unroll
        for (int p = 0; p < NPROJ; p++) {
            pmn[p] = fminf(pmn[p], __shfl_xor(pmn[p], o));
            pmx[p] = fmaxf(pmx[p], __shfl_xor(pmx[p], o));
        }
    }
    int lane = tid & 63, wv = tid >> 6;
    if (lane == 0) {
#pragma unroll
        for (int p = 0; p < NPROJ; p++) { smn[wv][p] = pmn[p]; smx[wv][p] = pmx[p]; }
    }
    __syncthreads();
    if (tid < NPROJ) {
        float mn = fminf(fminf(smn[0][tid], smn[1][tid]), fminf(smn[2][tid], smn[3][tid]));
        float mx = fmaxf(fmaxf(smx[0][tid], smx[1][tid]), fmaxf(smx[2][tid], smx[3][tid]));
        atomicMin(&keys[2 * (b * NPROJ + tid)], f2key(mn));
        atomicMax(&keys[2 * (b * NPROJ + tid) + 1], f2key(mx));
    }
}

// ---------- K2: y-hist scatter (idempotent plain stores, float4 reads) -------
__global__ __launch_bounds__(256) void k_scatter(const float* __restrict__ py,
                                                 const unsigned* __restrict__ keys,
                                                 float* __restrict__ hist) {
    int bp = blockIdx.y;
    float mn = key2f(keys[2 * bp]);
    float sc = key2f(keys[2 * bp + 1]) - mn;
    const float4* src = (const float4*)(py + (size_t)bp * NPAT);
    float* h = hist + (size_t)bp * NB2 + 8;
    const int n4 = NPAT / 4;
    for (int i = blockIdx.x * blockDim.x + threadIdx.x; i < n4;
         i += gridDim.x * blockDim.x) {
        float4 v = src[i];
        float vv[4] = { v.x, v.y, v.z, v.w };
#pragma unroll
        for (int j = 0; j < 4; j++) {
            int idx = (int)floorf(65535.f * (vv[j] - mn) / sc);
            h[min(max(idx, 0), 65535)] = 1.f;
        }
    }
}

// conv-on-the-fly bilinear gather: smooth[w] = min(sum_k g[k]*hist[w+k], 1)
__device__ inline float gath(const float* __restrict__ h, float v, float mn, float sc,
                             const float g[7]) {
    float t = (v - mn) / sc;                 // in [0,1]
    float ix = t * (float)WD - 0.5f;
    float x0 = floorf(ix);
    float w1 = ix - x0;
    int x0i = (int)x0;                       // in [-1, WD-1]; pads make reads safe
    float hv[8];
#pragma unroll
    for (int j = 0; j < 8; j++) hv[j] = h[x0i + j];
    float s0 = 0.f, s1 = 0.f;
#pragma unroll
    for (int k = 0; k < 7; k++) { s0 = fmaf(g[k], hv[k], s0); s1 = fmaf(g[k], hv[k + 1], s1); }
    s0 = fminf(s0, 1.f);
    s1 = fminf(s1, 1.f);
    float r0 = (x0i >= 0) ? s0 : 0.f;        // x0i <= WD-1 guaranteed (t<=1)
    float r1 = (x0i + 1 < WD) ? s1 : 0.f;    // x0i+1 >= 0 guaranteed
    return r0 * (1.f - w1) + r1 * w1;
}

// ---------- K3: gather + on-the-fly conv + clamp + blend + reduce ------------
__global__ __launch_bounds__(256) void k_gatherconv(const float* __restrict__ px,
                                                    const unsigned* __restrict__ keys,
                                                    const float* __restrict__ hist,
                                                    float* __restrict__ out) {
    int bp = blockIdx.y;
    float mn = key2f(keys[2 * bp]);
    float sc = key2f(keys[2 * bp + 1]) - mn;
    const float4* src = (const float4*)(px + (size_t)bp * NPAT);
    const float* h = hist + (size_t)bp * NB2 + 8;
    float g[7];
#pragma unroll
    for (int k = 0; k < 7; k++) {
        float d = (float)(k - 3);
        g[k] = expf(-(d * d) / 1.44f);   // exp((x)^2/(-2*1.2^2))**2
    }
    float acc = 0.f;
    const int n4 = NPAT / 4;
    for (int i = blockIdx.x * blockDim.x + threadIdx.x; i < n4;
         i += gridDim.x * blockDim.x) {
        float4 v = src[i];
        acc += gath(h, v.x, mn, sc, g);
        acc += gath(h, v.y, mn, sc, g);
        acc += gath(h, v.z, mn, sc, g);
        acc += gath(h, v.w, mn, sc, g);
    }
    for (int o = 32; o > 0; o >>= 1) acc += __shfl_down(acc, o);
    __shared__ float sacc[4];
    int wv = threadIdx.x >> 6;
    if ((threadIdx.x & 63) == 0) sacc[wv] = acc;
    __syncthreads();
    if (threadIdx.x == 0) {
        float t = sacc[0] + sacc[1] + sacc[2] + sacc[3];
        atomicAdd(out, -t * (1.0f / 32.0f));   // mean over B*NPROJ, negated
    }
}

extern "C" void kernel_launch(void* const* d_in, const int* in_sizes, int n_in,
                              void* d_out, int out_size, void* d_ws, size_t ws_size,
                              hipStream_t stream) {
    (void)in_sizes; (void)n_in; (void)out_size; (void)ws_size;
    const float* x = (const float*)d_in[0];
    const float* y = (const float*)d_in[1];
    const float* rnd = (const float*)d_in[2];
    float* out = (float*)d_out;

    float* ws = (float*)d_ws;
    float* rnorm = ws;                                     // 4704 floats
    float* px = rnorm + (size_t)B_ * DF * NPROJ;           // BP*NPAT
    float* py = px + (size_t)BP * NPAT;                    // BP*NPAT
    float* hist = py + (size_t)BP * NPAT;                  // BP*NB2 (padded)
    unsigned* keys = (unsigned*)(hist + (size_t)BP * NB2); // 2*BP

    k_rnorm<<<BP, 64, 0, stream>>>(rnd, rnorm, keys, out);
    hipMemsetAsync(hist, 0, (size_t)BP * NB2 * sizeof(float), stream);

    dim3 pgrid((HO + 31) / 32, (HO + 31) / 32, 2 * B_);
    k_proj<<<pgrid, 256, 0, stream>>>(x, y, rnorm, px, py, keys);

    k_scatter<<<dim3(128, BP), 256, 0, stream>>>(py, keys, hist);
    k_gatherconv<<<dim3(128, BP), 256, 0, stream>>>(px, keys, hist, out);
}

// Round 5
// 133.420 us; speedup vs baseline: 4.5213x; 1.2154x over previous
//
#include <hip/hip_runtime.h>
#include <math.h>
#include <stdint.h>

#define NPROJ 16
#define NBINS 65536
#define WD (NBINS - 6)
#define HB 65560              // hist byte stride/bp: 8 front pad + 65536 + 16 back pad
#define B_ 2
#define C_ 3
#define H_ 384
#define W_ 384
#define HO 378
#define NPAT (HO * HO)        // 142884 (div by 4)
#define DF 147                // 3*7*7
#define BP 32                 // B_*NPROJ

__device__ inline unsigned f2key(float f) {
    unsigned u = __float_as_uint(f);
    return (u & 0x80000000u) ? ~u : (u | 0x80000000u);
}
__device__ inline float key2f(unsigned k) {
    unsigned u = (k & 0x80000000u) ? (k ^ 0x80000000u) : ~k;
    return __uint_as_float(u);
}

// ---------- K0: rand/std (ddof=1); init keys; zero out -----------------------
__global__ __launch_bounds__(64) void k_rnorm(const float* __restrict__ rnd,
                                              float* __restrict__ rnorm,
                                              unsigned* __restrict__ keys,
                                              float* __restrict__ out) {
    int bp = blockIdx.x;
    int b = bp / NPROJ, p = bp % NPROJ;
    int lane = threadIdx.x;
    if (lane == 0) {
        keys[2 * bp] = 0xFFFFFFFFu;
        keys[2 * bp + 1] = 0u;
        if (bp == 0) out[0] = 0.f;     // accumulated atomically in K3
    }
    float s = 0.f, s2 = 0.f;
    for (int d = lane; d < DF; d += 64) {
        float v = rnd[((size_t)b * DF + d) * NPROJ + p];
        s += v; s2 += v * v;
    }
    for (int o = 32; o > 0; o >>= 1) { s += __shfl_down(s, o); s2 += __shfl_down(s2, o); }
    s = __shfl(s, 0); s2 = __shfl(s2, 0);
    float mean = s / (float)DF;
    float var = (s2 - (float)DF * mean * mean) / (float)(DF - 1);
    float inv = 1.0f / sqrtf(var);
    for (int d = lane; d < DF; d += 64) {
        size_t idx = ((size_t)b * DF + d) * NPROJ + p;
        rnorm[idx] = rnd[idx] * inv;
    }
}

// ---------- K1: proj both images; min/max atomics; store py ONLY -------------
// tile 32(h)x16(w), 256 threads, 2 outputs/thread. grid (24,12,4):
// z = b*2 + isy. x-slices contribute min/max only (values recomputed in K3).
#define T1H 32
#define T1W 16
__global__ __launch_bounds__(256) void k_projmm(const float* __restrict__ ximg,
                                                const float* __restrict__ yimg,
                                                const float* __restrict__ rnorm,
                                                float* __restrict__ py,
                                                unsigned* __restrict__ keys) {
    __shared__ float tile[C_][T1H + 6][T1W + 6];   // [3][38][22]
    __shared__ float wlds[DF][NPROJ];
    __shared__ float red_mn[4][NPROJ], red_mx[4][NPROJ];
    int bz = blockIdx.z;
    int b = bz >> 1, isy = bz & 1;
    const float* img = isy ? yimg : ximg;
    int tid = threadIdx.x;
    int tx = tid & 15, ty = tid >> 4;              // 16x16 threads, 2 rows apart 16
    int h0 = blockIdx.y * T1H, w0 = blockIdx.x * T1W;

    for (int i = tid; i < DF * NPROJ; i += 256)
        ((float*)wlds)[i] = rnorm[(size_t)b * DF * NPROJ + i];
    for (int c = 0; c < C_; c++)
        for (int i = tid; i < (T1H + 6) * (T1W + 6); i += 256) {
            int r = i / (T1W + 6), col = i % (T1W + 6);
            int h = h0 + r, w = w0 + col;
            tile[c][r][col] = (h < H_ && w < W_)
                ? img[((size_t)(b * C_ + c) * H_ + h) * W_ + w] : 0.f;
        }
    __syncthreads();

    float acc[2][NPROJ];
#pragma unroll
    for (int q = 0; q < 2; q++)
#pragma unroll
        for (int p = 0; p < NPROJ; p++) acc[q][p] = 0.f;

    for (int c = 0; c < C_; c++)
        for (int i = 0; i < 7; i++)
#pragma unroll
            for (int j = 0; j < 7; j++) {
                const float* wp = &wlds[c * 49 + i * 7 + j][0];
                float wv[NPROJ];
#pragma unroll
                for (int p = 0; p < NPROJ; p++) wv[p] = wp[p];
                float pix0 = tile[c][ty + i][tx + j];
                float pix1 = tile[c][ty + 16 + i][tx + j];
#pragma unroll
                for (int p = 0; p < NPROJ; p++) {
                    acc[0][p] = fmaf(pix0, wv[p], acc[0][p]);
                    acc[1][p] = fmaf(pix1, wv[p], acc[1][p]);
                }
            }

    int wo = w0 + tx;
    int ho0 = h0 + ty, ho1 = h0 + ty + 16;
    bool vm0 = (ho0 < HO) && (wo < HO);
    bool vm1 = (ho1 < HO) && (wo < HO);

    if (isy) {
        if (vm0) {
            size_t n = (size_t)ho0 * HO + wo;
#pragma unroll
            for (int p = 0; p < NPROJ; p++)
                py[((size_t)(b * NPROJ + p)) * NPAT + n] = acc[0][p];
        }
        if (vm1) {
            size_t n = (size_t)ho1 * HO + wo;
#pragma unroll
            for (int p = 0; p < NPROJ; p++)
                py[((size_t)(b * NPROJ + p)) * NPAT + n] = acc[1][p];
        }
    }

    float pmn[NPROJ], pmx[NPROJ];
#pragma unroll
    for (int p = 0; p < NPROJ; p++) {
        float mn = INFINITY, mx = -INFINITY;
        if (vm0) { mn = acc[0][p]; mx = acc[0][p]; }
        if (vm1) { mn = fminf(mn, acc[1][p]); mx = fmaxf(mx, acc[1][p]); }
        pmn[p] = mn; pmx[p] = mx;
    }
#pragma unroll
    for (int o = 1; o < 64; o <<= 1) {
#pragma unroll
        for (int p = 0; p < NPROJ; p++) {
            pmn[p] = fminf(pmn[p], __shfl_xor(pmn[p], o));
            pmx[p] = fmaxf(pmx[p], __shfl_xor(pmx[p], o));
        }
    }
    int wv4 = tid >> 6;
    if ((tid & 63) == 0) {
#pragma unroll
        for (int p = 0; p < NPROJ; p++) { red_mn[wv4][p] = pmn[p]; red_mx[wv4][p] = pmx[p]; }
    }
    __syncthreads();
    if (tid < NPROJ) {
        float mn = fminf(fminf(red_mn[0][tid], red_mn[1][tid]),
                         fminf(red_mn[2][tid], red_mn[3][tid]));
        float mx = fmaxf(fmaxf(red_mx[0][tid], red_mx[1][tid]),
                         fmaxf(red_mx[2][tid], red_mx[3][tid]));
        atomicMin(&keys[2 * (b * NPROJ + tid)], f2key(mn));
        atomicMax(&keys[2 * (b * NPROJ + tid) + 1], f2key(mx));
    }
}

// ---------- K2: y-hist scatter into uint8 flags (idempotent byte stores) -----
__global__ __launch_bounds__(256) void k_scatter(const float* __restrict__ py,
                                                 const unsigned* __restrict__ keys,
                                                 uint8_t* __restrict__ hist8) {
    int bp = blockIdx.y;
    float mn = key2f(keys[2 * bp]);
    float sc = key2f(keys[2 * bp + 1]) - mn;
    const float4* src = (const float4*)(py + (size_t)bp * NPAT);
    uint8_t* h = hist8 + (size_t)bp * HB + 8;
    const int n4 = NPAT / 4;
    for (int i = blockIdx.x * blockDim.x + threadIdx.x; i < n4;
         i += gridDim.x * blockDim.x) {
        float4 v = src[i];
        int i0 = (int)floorf(65535.f * (v.x - mn) / sc);
        int i1 = (int)floorf(65535.f * (v.y - mn) / sc);
        int i2 = (int)floorf(65535.f * (v.z - mn) / sc);
        int i3 = (int)floorf(65535.f * (v.w - mn) / sc);
        h[min(max(i0, 0), 65535)] = 1;
        h[min(max(i1, 0), 65535)] = 1;
        h[min(max(i2, 0), 65535)] = 1;
        h[min(max(i3, 0), 65535)] = 1;
    }
}

// ---------- K3: recompute x-proj (bit-identical) + gather + reduce -----------
// tile 16x16, 256 threads, 1 output/thread. grid (24,24,B_).
#define T3 16
__global__ __launch_bounds__(256) void k_projgather(const float* __restrict__ ximg,
                                                    const float* __restrict__ rnorm,
                                                    const unsigned* __restrict__ keys,
                                                    const uint8_t* __restrict__ hist8,
                                                    float* __restrict__ out) {
    __shared__ float tile[C_][T3 + 6][T3 + 6];   // [3][22][22]
    __shared__ float wlds[DF][NPROJ];
    __shared__ float s_mn[NPROJ], s_sc[NPROJ];
    __shared__ float sred[4];
    int b = blockIdx.z;
    int tid = threadIdx.x;
    int tx = tid & 15, ty = tid >> 4;
    int h0 = blockIdx.y * T3, w0 = blockIdx.x * T3;

    if (tid < NPROJ) {
        float mn = key2f(keys[2 * (b * NPROJ + tid)]);
        float mx = key2f(keys[2 * (b * NPROJ + tid) + 1]);
        s_mn[tid] = mn;
        s_sc[tid] = mx - mn;
    }
    for (int i = tid; i < DF * NPROJ; i += 256)
        ((float*)wlds)[i] = rnorm[(size_t)b * DF * NPROJ + i];
    for (int c = 0; c < C_; c++)
        for (int i = tid; i < (T3 + 6) * (T3 + 6); i += 256) {
            int r = i / (T3 + 6), col = i % (T3 + 6);
            int h = h0 + r, w = w0 + col;
            tile[c][r][col] = (h < H_ && w < W_)
                ? ximg[((size_t)(b * C_ + c) * H_ + h) * W_ + w] : 0.f;
        }
    __syncthreads();

    float acc[NPROJ];
#pragma unroll
    for (int p = 0; p < NPROJ; p++) acc[p] = 0.f;

    for (int c = 0; c < C_; c++)
        for (int i = 0; i < 7; i++)
#pragma unroll
            for (int j = 0; j < 7; j++) {
                const float* wp = &wlds[c * 49 + i * 7 + j][0];
                float wv[NPROJ];
#pragma unroll
                for (int p = 0; p < NPROJ; p++) wv[p] = wp[p];
                float pix = tile[c][ty + i][tx + j];
#pragma unroll
                for (int p = 0; p < NPROJ; p++)
                    acc[p] = fmaf(pix, wv[p], acc[p]);
            }

    float g[7];
#pragma unroll
    for (int k = 0; k < 7; k++) {
        float d = (float)(k - 3);
        g[k] = expf(-(d * d) / 1.44f);   // exp((x)^2/(-2*1.2^2))**2
    }

    int wo = w0 + tx, ho = h0 + ty;
    float lacc = 0.f;
    if (ho < HO && wo < HO) {
#pragma unroll
        for (int p = 0; p < NPROJ; p++) {
            float v = acc[p];
            float t = (v - s_mn[p]) / s_sc[p];       // in [0,1]
            float ix = t * (float)WD - 0.5f;
            float x0 = floorf(ix);
            float w1 = ix - x0;
            int x0i = (int)x0;                        // [-1, WD-1]
            int b0 = 8 + x0i;                         // byte off in slice, >= 7
            int d0 = b0 >> 2, off = b0 & 3;
            const uint32_t* hw =
                (const uint32_t*)(hist8 + (size_t)(b * NPROJ + p) * HB);
            uint32_t u0 = hw[d0], u1 = hw[d0 + 1], u2 = hw[d0 + 2];
            uint64_t lo = (uint64_t)u0 | ((uint64_t)u1 << 32);
            int sh = off * 8;
            // bytes b0..b0+7 of the slice, branchless (each shift <= 63)
            uint64_t w8 = (lo >> sh) | ((((uint64_t)u2) << 1) << (63 - sh));
            float f0 = (float)((uint32_t)(w8      ) & 1u);
            float f1 = (float)((uint32_t)(w8 >>  8) & 1u);
            float f2 = (float)((uint32_t)(w8 >> 16) & 1u);
            float f3 = (float)((uint32_t)(w8 >> 24) & 1u);
            float f4 = (float)((uint32_t)(w8 >> 32) & 1u);
            float f5 = (float)((uint32_t)(w8 >> 40) & 1u);
            float f6 = (float)((uint32_t)(w8 >> 48) & 1u);
            float f7 = (float)((uint32_t)(w8 >> 56) & 1u);
            float s0 = g[0] * f0 + g[1] * f1 + g[2] * f2 + g[3] * f3
                     + g[4] * f4 + g[5] * f5 + g[6] * f6;
            float s1 = g[0] * f1 + g[1] * f2 + g[2] * f3 + g[3] * f4
                     + g[4] * f5 + g[5] * f6 + g[6] * f7;
            s0 = fminf(s0, 1.f);
            s1 = fminf(s1, 1.f);
            float r0 = (x0i >= 0) ? s0 : 0.f;
            float r1 = (x0i + 1 < WD) ? s1 : 0.f;
            lacc += r0 * (1.f - w1) + r1 * w1;
        }
    }
    for (int o = 32; o > 0; o >>= 1) lacc += __shfl_down(lacc, o);
    int wv4 = tid >> 6;
    if ((tid & 63) == 0) sred[wv4] = lacc;
    __syncthreads();
    if (tid == 0) {
        float t = sred[0] + sred[1] + sred[2] + sred[3];
        atomicAdd(out, -t * (1.0f / 32.0f));
    }
}

extern "C" void kernel_launch(void* const* d_in, const int* in_sizes, int n_in,
                              void* d_out, int out_size, void* d_ws, size_t ws_size,
                              hipStream_t stream) {
    (void)in_sizes; (void)n_in; (void)out_size; (void)ws_size;
    const float* x = (const float*)d_in[0];
    const float* y = (const float*)d_in[1];
    const float* rnd = (const float*)d_in[2];
    float* out = (float*)d_out;

    float* ws = (float*)d_ws;
    float* rnorm = ws;                                     // 4704 floats
    float* py = rnorm + (size_t)B_ * DF * NPROJ;           // BP*NPAT floats
    unsigned* keys = (unsigned*)(py + (size_t)BP * NPAT);  // 2*BP
    uint8_t* hist8 = (uint8_t*)(keys + 2 * BP);            // BP*HB bytes

    k_rnorm<<<BP, 64, 0, stream>>>(rnd, rnorm, keys, out);
    hipMemsetAsync(hist8, 0, (size_t)BP * HB, stream);

    dim3 g1(384 / T1W, 384 / T1H, 2 * B_);                 // (24,12,4)
    k_projmm<<<g1, 256, 0, stream>>>(x, y, rnorm, py, keys);

    k_scatter<<<dim3(70, BP), 256, 0, stream>>>(py, keys, hist8);

    dim3 g3(384 / T3, 384 / T3, B_);                       // (24,24,2)
    k_projgather<<<g3, 256, 0, stream>>>(x, rnorm, keys, hist8, out);
}

// Round 6
// 119.874 us; speedup vs baseline: 5.0322x; 1.1130x over previous
//
#include <hip/hip_runtime.h>
#include <math.h>
#include <stdint.h>

#define NPROJ 16
#define NBINS 65536
#define WD (NBINS - 6)
#define HB 65560              // hist byte stride/bp: 8 front pad + 65536 + 16 back pad
#define B_ 2
#define C_ 3
#define H_ 384
#define W_ 384
#define HO 378
#define NPAT (HO * HO)        // 142884 (div by 4)
#define DF 147                // 3*7*7
#define BP 32                 // B_*NPROJ
#define TSTR 24               // LDS tile row stride: (24r+col)%32 -> uniform 2-way

__device__ inline unsigned f2key(float f) {
    unsigned u = __float_as_uint(f);
    return (u & 0x80000000u) ? ~u : (u | 0x80000000u);
}
__device__ inline float key2f(unsigned k) {
    unsigned u = (k & 0x80000000u) ? (k ^ 0x80000000u) : ~k;
    return __uint_as_float(u);
}

// ---------- K0: rand/std (ddof=1); init keys; zero out -----------------------
__global__ __launch_bounds__(64) void k_rnorm(const float* __restrict__ rnd,
                                              float* __restrict__ rnorm,
                                              unsigned* __restrict__ keys,
                                              float* __restrict__ out) {
    int bp = blockIdx.x;
    int b = bp / NPROJ, p = bp % NPROJ;
    int lane = threadIdx.x;
    if (lane == 0) {
        keys[2 * bp] = 0xFFFFFFFFu;
        keys[2 * bp + 1] = 0u;
        if (bp == 0) out[0] = 0.f;     // accumulated atomically in K3
    }
    float s = 0.f, s2 = 0.f;
    for (int d = lane; d < DF; d += 64) {
        float v = rnd[((size_t)b * DF + d) * NPROJ + p];
        s += v; s2 += v * v;
    }
    for (int o = 32; o > 0; o >>= 1) { s += __shfl_down(s, o); s2 += __shfl_down(s2, o); }
    s = __shfl(s, 0); s2 = __shfl(s2, 0);
    float mean = s / (float)DF;
    float var = (s2 - (float)DF * mean * mean) / (float)(DF - 1);
    float inv = 1.0f / sqrtf(var);
    for (int d = lane; d < DF; d += 64) {
        size_t idx = ((size_t)b * DF + d) * NPROJ + p;
        rnorm[idx] = rnd[idx] * inv;
    }
}

// ---------- K1: proj both images; min/max atomics; store py ONLY -------------
// tile 32(h)x16(w), 256 threads, 2 outputs/thread. grid (24,12,4):
// z = b*2 + isy. Weights read via wave-uniform global addrs (s_load/K$),
// NOT LDS -> LDS bandwidth reserved for pixel reads.
#define T1H 32
#define T1W 16
__global__ __launch_bounds__(256) void k_projmm(const float* __restrict__ ximg,
                                                const float* __restrict__ yimg,
                                                const float* __restrict__ rnorm,
                                                float* __restrict__ py,
                                                unsigned* __restrict__ keys) {
    __shared__ float tile[C_][T1H + 6][TSTR];   // [3][38][24]
    __shared__ float red_mn[4][NPROJ], red_mx[4][NPROJ];
    int bz = blockIdx.z;
    int b = bz >> 1, isy = bz & 1;
    const float* img = isy ? yimg : ximg;
    int tid = threadIdx.x;
    int tx = tid & 15, ty = tid >> 4;              // 16x16 threads, rows 16 apart
    int h0 = blockIdx.y * T1H, w0 = blockIdx.x * T1W;

    for (int c = 0; c < C_; c++)
        for (int i = tid; i < (T1H + 6) * (T1W + 6); i += 256) {
            int r = i / (T1W + 6), col = i % (T1W + 6);
            int h = h0 + r, w = w0 + col;
            tile[c][r][col] = (h < H_ && w < W_)
                ? img[((size_t)(b * C_ + c) * H_ + h) * W_ + w] : 0.f;
        }
    __syncthreads();

    const float* wbase = rnorm + (size_t)b * DF * NPROJ;

    float acc[2][NPROJ];
#pragma unroll
    for (int q = 0; q < 2; q++)
#pragma unroll
        for (int p = 0; p < NPROJ; p++) acc[q][p] = 0.f;

    for (int c = 0; c < C_; c++)
        for (int i = 0; i < 7; i++)
#pragma unroll
            for (int j = 0; j < 7; j++) {
                const float* wrow = wbase + (c * 49 + i * 7 + j) * NPROJ; // uniform
                float wv[NPROJ];
#pragma unroll
                for (int p = 0; p < NPROJ; p++) wv[p] = wrow[p];          // s_load
                float pix0 = tile[c][ty + i][tx + j];
                float pix1 = tile[c][ty + 16 + i][tx + j];
#pragma unroll
                for (int p = 0; p < NPROJ; p++) {
                    acc[0][p] = fmaf(pix0, wv[p], acc[0][p]);
                    acc[1][p] = fmaf(pix1, wv[p], acc[1][p]);
                }
            }

    int wo = w0 + tx;
    int ho0 = h0 + ty, ho1 = h0 + ty + 16;
    bool vm0 = (ho0 < HO) && (wo < HO);
    bool vm1 = (ho1 < HO) && (wo < HO);

    if (isy) {
        if (vm0) {
            size_t n = (size_t)ho0 * HO + wo;
#pragma unroll
            for (int p = 0; p < NPROJ; p++)
                py[((size_t)(b * NPROJ + p)) * NPAT + n] = acc[0][p];
        }
        if (vm1) {
            size_t n = (size_t)ho1 * HO + wo;
#pragma unroll
            for (int p = 0; p < NPROJ; p++)
                py[((size_t)(b * NPROJ + p)) * NPAT + n] = acc[1][p];
        }
    }

    float pmn[NPROJ], pmx[NPROJ];
#pragma unroll
    for (int p = 0; p < NPROJ; p++) {
        float mn = INFINITY, mx = -INFINITY;
        if (vm0) { mn = acc[0][p]; mx = acc[0][p]; }
        if (vm1) { mn = fminf(mn, acc[1][p]); mx = fmaxf(mx, acc[1][p]); }
        pmn[p] = mn; pmx[p] = mx;
    }
#pragma unroll
    for (int o = 1; o < 64; o <<= 1) {
#pragma unroll
        for (int p = 0; p < NPROJ; p++) {
            pmn[p] = fminf(pmn[p], __shfl_xor(pmn[p], o));
            pmx[p] = fmaxf(pmx[p], __shfl_xor(pmx[p], o));
        }
    }
    int wv4 = tid >> 6;
    if ((tid & 63) == 0) {
#pragma unroll
        for (int p = 0; p < NPROJ; p++) { red_mn[wv4][p] = pmn[p]; red_mx[wv4][p] = pmx[p]; }
    }
    __syncthreads();
    if (tid < NPROJ) {
        float mn = fminf(fminf(red_mn[0][tid], red_mn[1][tid]),
                         fminf(red_mn[2][tid], red_mn[3][tid]));
        float mx = fmaxf(fmaxf(red_mx[0][tid], red_mx[1][tid]),
                         fmaxf(red_mx[2][tid], red_mx[3][tid]));
        atomicMin(&keys[2 * (b * NPROJ + tid)], f2key(mn));
        atomicMax(&keys[2 * (b * NPROJ + tid) + 1], f2key(mx));
    }
}

// ---------- K2: y-hist scatter into uint8 flags (idempotent byte stores) -----
__global__ __launch_bounds__(256) void k_scatter(const float* __restrict__ py,
                                                 const unsigned* __restrict__ keys,
                                                 uint8_t* __restrict__ hist8) {
    int bp = blockIdx.y;
    float mn = key2f(keys[2 * bp]);
    float sc = key2f(keys[2 * bp + 1]) - mn;
    const float4* src = (const float4*)(py + (size_t)bp * NPAT);
    uint8_t* h = hist8 + (size_t)bp * HB + 8;
    const int n4 = NPAT / 4;
    for (int i = blockIdx.x * blockDim.x + threadIdx.x; i < n4;
         i += gridDim.x * blockDim.x) {
        float4 v = src[i];
        int i0 = (int)floorf(65535.f * (v.x - mn) / sc);
        int i1 = (int)floorf(65535.f * (v.y - mn) / sc);
        int i2 = (int)floorf(65535.f * (v.z - mn) / sc);
        int i3 = (int)floorf(65535.f * (v.w - mn) / sc);
        h[min(max(i0, 0), 65535)] = 1;
        h[min(max(i1, 0), 65535)] = 1;
        h[min(max(i2, 0), 65535)] = 1;
        h[min(max(i3, 0), 65535)] = 1;
    }
}

// ---------- K3: recompute x-proj (bit-identical) + gather + reduce -----------
// tile 16x16, 256 threads, 1 output/thread. grid (24,24,B_).
#define T3 16
__global__ __launch_bounds__(256) void k_projgather(const float* __restrict__ ximg,
                                                    const float* __restrict__ rnorm,
                                                    const unsigned* __restrict__ keys,
                                                    const uint8_t* __restrict__ hist8,
                                                    float* __restrict__ out) {
    __shared__ float tile[C_][T3 + 6][TSTR];   // [3][22][24]
    __shared__ float s_mn[NPROJ], s_sc[NPROJ];
    __shared__ float sred[4];
    int b = blockIdx.z;
    int tid = threadIdx.x;
    int tx = tid & 15, ty = tid >> 4;
    int h0 = blockIdx.y * T3, w0 = blockIdx.x * T3;

    if (tid < NPROJ) {
        float mn = key2f(keys[2 * (b * NPROJ + tid)]);
        float mx = key2f(keys[2 * (b * NPROJ + tid) + 1]);
        s_mn[tid] = mn;
        s_sc[tid] = mx - mn;
    }
    for (int c = 0; c < C_; c++)
        for (int i = tid; i < (T3 + 6) * (T3 + 6); i += 256) {
            int r = i / (T3 + 6), col = i % (T3 + 6);
            int h = h0 + r, w = w0 + col;
            tile[c][r][col] = (h < H_ && w < W_)
                ? ximg[((size_t)(b * C_ + c) * H_ + h) * W_ + w] : 0.f;
        }
    __syncthreads();

    const float* wbase = rnorm + (size_t)b * DF * NPROJ;

    float acc[NPROJ];
#pragma unroll
    for (int p = 0; p < NPROJ; p++) acc[p] = 0.f;

    for (int c = 0; c < C_; c++)
        for (int i = 0; i < 7; i++)
#pragma unroll
            for (int j = 0; j < 7; j++) {
                const float* wrow = wbase + (c * 49 + i * 7 + j) * NPROJ; // uniform
                float wv[NPROJ];
#pragma unroll
                for (int p = 0; p < NPROJ; p++) wv[p] = wrow[p];          // s_load
                float pix = tile[c][ty + i][tx + j];
#pragma unroll
                for (int p = 0; p < NPROJ; p++)
                    acc[p] = fmaf(pix, wv[p], acc[p]);
            }

    float g[7];
#pragma unroll
    for (int k = 0; k < 7; k++) {
        float d = (float)(k - 3);
        g[k] = expf(-(d * d) / 1.44f);   // exp((x)^2/(-2*1.2^2))**2
    }

    int wo = w0 + tx, ho = h0 + ty;
    float lacc = 0.f;
    if (ho < HO && wo < HO) {
#pragma unroll
        for (int p = 0; p < NPROJ; p++) {
            float v = acc[p];
            float t = (v - s_mn[p]) / s_sc[p];       // in [0,1]
            float ix = t * (float)WD - 0.5f;
            float x0 = floorf(ix);
            float w1 = ix - x0;
            int x0i = (int)x0;                        // [-1, WD-1]
            int b0 = 8 + x0i;                         // byte off in slice, >= 7
            int d0 = b0 >> 2, off = b0 & 3;
            const uint32_t* hw =
                (const uint32_t*)(hist8 + (size_t)(b * NPROJ + p) * HB);
            uint32_t u0 = hw[d0], u1 = hw[d0 + 1], u2 = hw[d0 + 2];
            uint64_t lo = (uint64_t)u0 | ((uint64_t)u1 << 32);
            int sh = off * 8;
            // bytes b0..b0+7 of the slice, branchless (each shift <= 63)
            uint64_t w8 = (lo >> sh) | ((((uint64_t)u2) << 1) << (63 - sh));
            float f0 = (float)((uint32_t)(w8      ) & 1u);
            float f1 = (float)((uint32_t)(w8 >>  8) & 1u);
            float f2 = (float)((uint32_t)(w8 >> 16) & 1u);
            float f3 = (float)((uint32_t)(w8 >> 24) & 1u);
            float f4 = (float)((uint32_t)(w8 >> 32) & 1u);
            float f5 = (float)((uint32_t)(w8 >> 40) & 1u);
            float f6 = (float)((uint32_t)(w8 >> 48) & 1u);
            float f7 = (float)((uint32_t)(w8 >> 56) & 1u);
            float s0 = g[0] * f0 + g[1] * f1 + g[2] * f2 + g[3] * f3
                     + g[4] * f4 + g[5] * f5 + g[6] * f6;
            float s1 = g[0] * f1 + g[1] * f2 + g[2] * f3 + g[3] * f4
                     + g[4] * f5 + g[5] * f6 + g[6] * f7;
            s0 = fminf(s0, 1.f);
            s1 = fminf(s1, 1.f);
            float r0 = (x0i >= 0) ? s0 : 0.f;
            float r1 = (x0i + 1 < WD) ? s1 : 0.f;
            lacc += r0 * (1.f - w1) + r1 * w1;
        }
    }
    for (int o = 32; o > 0; o >>= 1) lacc += __shfl_down(lacc, o);
    int wv4 = tid >> 6;
    if ((tid & 63) == 0) sred[wv4] = lacc;
    __syncthreads();
    if (tid == 0) {
        float t = sred[0] + sred[1] + sred[2] + sred[3];
        atomicAdd(out, -t * (1.0f / 32.0f));
    }
}

extern "C" void kernel_launch(void* const* d_in, const int* in_sizes, int n_in,
                              void* d_out, int out_size, void* d_ws, size_t ws_size,
                              hipStream_t stream) {
    (void)in_sizes; (void)n_in; (void)out_size; (void)ws_size;
    const float* x = (const float*)d_in[0];
    const float* y = (const float*)d_in[1];
    const float* rnd = (const float*)d_in[2];
    float* out = (float*)d_out;

    float* ws = (float*)d_ws;
    float* rnorm = ws;                                     // 4704 floats
    float* py = rnorm + (size_t)B_ * DF * NPROJ;           // BP*NPAT floats
    unsigned* keys = (unsigned*)(py + (size_t)BP * NPAT);  // 2*BP
    uint8_t* hist8 = (uint8_t*)(keys + 2 * BP);            // BP*HB bytes

    k_rnorm<<<BP, 64, 0, stream>>>(rnd, rnorm, keys, out);
    hipMemsetAsync(hist8, 0, (size_t)BP * HB, stream);

    dim3 g1(384 / T1W, 384 / T1H, 2 * B_);                 // (24,12,4)
    k_projmm<<<g1, 256, 0, stream>>>(x, y, rnorm, py, keys);

    k_scatter<<<dim3(70, BP), 256, 0, stream>>>(py, keys, hist8);

    dim3 g3(384 / T3, 384 / T3, B_);                       // (24,24,2)
    k_projgather<<<g3, 256, 0, stream>>>(x, rnorm, keys, hist8, out);
}